// Round 5
// baseline (507.875 us; speedup 1.0000x reference)
//
#include <hip/hip_runtime.h>

// Problem constants (fixed shapes from reference setup_inputs)
#define N_INST 32768
#define DIM    2048
#define DP     512
#define NCLS   4

typedef _Float16 half8_t  __attribute__((ext_vector_type(8)));
typedef float    float4_t __attribute__((ext_vector_type(4)));

// Workspace layout (bytes). Total ~2.6 MB.
#define OFF_UHI   0ull                               // DP*DIM fp16 = 2 MB
#define OFF_SP    (OFF_UHI + (size_t)DP*DIM*2)       // 4*N fp32 partial scores = 512 KB
#define OFF_PSTAT (OFF_SP  + (size_t)4*N_INST*4)     // 514 fp32 (per-block stats + global)
#define OFF_CTL   (OFF_PSTAT + 4096ull)              // 2 ints (arrive count, flag)

__device__ __forceinline__ float tanh_fast(float x) {
  // tanh(x) = 1 - 2/(exp(2x)+1); exp overflow->inf gives exact +/-1 limits
  float e = __expf(2.0f * x);
  return 1.0f - 2.0f / (e + 1.0f);
}

// async global->LDS, 16B per lane. LDS dest is wave-uniform base; HW adds lane*16.
typedef const unsigned int __attribute__((address_space(1)))* gas_t;
typedef unsigned int       __attribute__((address_space(3)))* las_t;
__device__ __forceinline__ void gl16(const void* g, void* l) {
  __builtin_amdgcn_global_load_lds((gas_t)g, (las_t)l, 16, 0, 0);
}

// ---- fp32 -> fp16 convert of U (8 elems/thread) + zero ctl/out ----
__global__ __launch_bounds__(256) void k_cvt(const float4* __restrict__ in,
                                             half8_t* __restrict__ outU,
                                             int* __restrict__ ctl,
                                             float* __restrict__ outv) {
  int i = blockIdx.x * 256 + threadIdx.x;     // 0..131071
  float4 a = in[2 * i], b = in[2 * i + 1];
  half8_t h;
  h[0] = (_Float16)a.x; h[1] = (_Float16)a.y;
  h[2] = (_Float16)a.z; h[3] = (_Float16)a.w;
  h[4] = (_Float16)b.x; h[5] = (_Float16)b.y;
  h[6] = (_Float16)b.z; h[7] = (_Float16)b.w;
  outU[i] = h;
  if (i == 0) {
    ctl[0] = 0; ctl[1] = 0;
    outv[0] = 0.f; outv[1] = 0.f; outv[2] = 0.f; outv[3] = 0.f;
  }
}

// ---- fused score GEMM, 128x128 tile, BK=64, 4 waves (2Mx2N), wave tile 64x64.
// sP[mb][n] = sum_{j in mb strip} Wmta[j]*tanh( Uhi[j,:] . V[n,:] )
// Key change vs R4: LDS 64 KB (dbuf of A 16KB + B 16KB fp16) -> 2 RESIDENT
// BLOCKS PER CU. The vmcnt(0)+barrier drain that stalled R4 (1 block/CU, all
// waves in one barrier group -> CU idles every K-step) now overlaps with the
// sibling block's compute phase (m114 co-scheduling). Grid 1024 = 4/CU queued,
// 2 resident. A via global_load_lds_dwordx4; B (V fp32) reg-staged with
// cvt_pkrtz -> fp16 ds_write, next-next-tile loads issued before COMPUTE (T14).
// Per-mb partial outputs (plain stores, no atomics, no pre-zeroing).
//
// Swizzle (proven 0-conflict in R4): 128B LDS rows = 8 16B-slots; physical
// slot p holds logical slot p^(row&7). A: pre-applied to the GLOBAL source
// address (gl_lds dest linear); B: applied to the ds_write address. Readers
// apply the same XOR.
__global__ __launch_bounds__(256, 2) void k_score_gemm(
    const _Float16* __restrict__ Uhi, const float* __restrict__ V,
    const float* __restrict__ Wmta, float* __restrict__ sP) {
  __shared__ _Float16 lA[2][128 * 64];   // 2 x 16 KB
  __shared__ _Float16 lB[2][128 * 64];   // 2 x 16 KB

  const int tid  = threadIdx.x;
  const int lane = tid & 63;
  const int wv   = tid >> 6;        // 0..3
  const int waveM = wv >> 1;        // 0..1
  const int waveN = wv & 1;         // 0..1
  const int quad = lane >> 4;       // 0..3
  const int col  = lane & 15;

  // XCD swizzle: 4 mb-siblings of one nb sit 8 apart in blockIdx (same XCD
  // under %8 round-robin) so a V n-strip is fetched ~once per XCD.
  const int b   = blockIdx.x;
  const int grp = b >> 5;
  const int win = b & 31;
  const int mb  = win >> 3;             // 0..3
  const int nb  = grp * 8 + (win & 7);  // 0..255

  const int aRow0  = mb * 128;
  const int bRow0  = nb * 128;
  const int kStart = (nb & 31) << 6;    // K-phase stagger

  // ---- A staging: 16 chunks of 1KB (8 rows x 128B); 4 chunks/wave ----
  const int rsub = lane >> 3;               // 0..7 row within chunk
  const int sswz = (lane & 7) ^ rsub;       // pre-swizzled source slot
  const _Float16* gA[4];
  int dA[4];                                 // element offset of chunk base
#pragma unroll
  for (int i2 = 0; i2 < 4; ++i2) {
    const int c = wv * 4 + i2;               // chunk 0..15
    gA[i2] = Uhi + (size_t)(aRow0 + c * 8 + rsub) * DIM + sswz * 8;
    dA[i2] = c * 512;
  }

  // ---- B staging: thread owns half a row (32 floats -> 32 fp16) ----
  const int rw = tid >> 1;                  // 0..127 (row = n within tile)
  const int hw = tid & 1;                   // which 32-float half
  const float* gB = V + (size_t)(bRow0 + rw) * DIM + hw * 32;
  int wOffB[4];                             // byte offsets (swizzled) in a bufB
#pragma unroll
  for (int p = 0; p < 4; ++p)
    wOffB[p] = rw * 128 + ((((hw << 2) | p) ^ (rw & 7)) << 4);

  // ---- fragment-read byte offsets (kh toggles byte^64 == logical slot^4) ----
  const int fsw = (quad ^ (col & 7)) << 4;
  int offA[4], offB[4];
#pragma unroll
  for (int mi = 0; mi < 4; ++mi)
    offA[mi] = (waveM * 64 + mi * 16 + col) * 128 + fsw;
#pragma unroll
  for (int ni = 0; ni < 4; ++ni)
    offB[ni] = (waveN * 64 + ni * 16 + col) * 128 + fsw;

  float4_t acc[4][4];
  const float4_t z4 = {0.f, 0.f, 0.f, 0.f};
#pragma unroll
  for (int i = 0; i < 4; i++)
#pragma unroll
    for (int j = 0; j < 4; j++) acc[i][j] = z4;

  float4 rb[8];   // in-flight B strip (32 floats)

#define KOF(t) ((kStart + (t) * 64) & (DIM - 1))

#define LOADB(kk) do {                                                     \
    const float4* p4 = (const float4*)(gB + (kk));                         \
    _Pragma("unroll")                                                      \
    for (int j = 0; j < 8; ++j) rb[j] = p4[j];                             \
  } while (0)

#define WRITEB(CUR) do {                                                   \
    char* base = (char*)&lB[CUR][0];                                       \
    _Pragma("unroll")                                                      \
    for (int p = 0; p < 4; ++p) {                                          \
      const auto c0 = __builtin_amdgcn_cvt_pkrtz(rb[2*p].x,   rb[2*p].y);  \
      const auto c1 = __builtin_amdgcn_cvt_pkrtz(rb[2*p].z,   rb[2*p].w);  \
      const auto c2 = __builtin_amdgcn_cvt_pkrtz(rb[2*p+1].x, rb[2*p+1].y);\
      const auto c3 = __builtin_amdgcn_cvt_pkrtz(rb[2*p+1].z, rb[2*p+1].w);\
      half8_t h;                                                           \
      h[0] = (_Float16)c0[0]; h[1] = (_Float16)c0[1];                      \
      h[2] = (_Float16)c1[0]; h[3] = (_Float16)c1[1];                      \
      h[4] = (_Float16)c2[0]; h[5] = (_Float16)c2[1];                      \
      h[6] = (_Float16)c3[0]; h[7] = (_Float16)c3[1];                      \
      *(half8_t*)(base + wOffB[p]) = h;                                    \
    }                                                                      \
  } while (0)

#define STAGEA(CUR, kk) do {                                               \
    gl16(gA[0] + (kk), &lA[CUR][dA[0]]);                                   \
    gl16(gA[1] + (kk), &lA[CUR][dA[1]]);                                   \
    gl16(gA[2] + (kk), &lA[CUR][dA[2]]);                                   \
    gl16(gA[3] + (kk), &lA[CUR][dA[3]]);                                   \
  } while (0)

#define COMPUTE(CUR) do {                                                  \
    const char* pA = (const char*)&lA[CUR][0];                             \
    const char* pB = (const char*)&lB[CUR][0];                             \
    _Pragma("unroll")                                                      \
    for (int kh = 0; kh < 2; ++kh) {                                       \
      half8_t af[4], bf[4];                                                \
      _Pragma("unroll")                                                    \
      for (int mi = 0; mi < 4; ++mi)                                       \
        af[mi] = *(const half8_t*)(pA + (offA[mi] ^ (kh << 6)));           \
      _Pragma("unroll")                                                    \
      for (int ni = 0; ni < 4; ++ni)                                       \
        bf[ni] = *(const half8_t*)(pB + (offB[ni] ^ (kh << 6)));           \
      _Pragma("unroll")                                                    \
      for (int mi = 0; mi < 4; ++mi)                                       \
        _Pragma("unroll")                                                  \
        for (int ni = 0; ni < 4; ++ni)                                     \
          acc[mi][ni] = __builtin_amdgcn_mfma_f32_16x16x32_f16(            \
              af[mi], bf[ni], acc[mi][ni], 0, 0, 0);                       \
    }                                                                      \
  } while (0)

  // ---- prologue: tile0 resident in buf0; rb holds tile1 ----
  LOADB(KOF(0));
  STAGEA(0, KOF(0));
  WRITEB(0);                    // compiler waits rb's vmcnt before cvt
  LOADB(KOF(1));
  __syncthreads();              // drains gl16 + ds_writes

  // ---- main loop: 32 K-tiles, 2 per trip, 1 barrier per tile ----
  for (int t = 0; t < 32; t += 2) {
    if (t < 31)  { STAGEA(1, KOF(t + 1)); WRITEB(1); }   // rb = tile t+1
    if (t < 30)  LOADB(KOF(t + 2));                      // issue early (T14)
    COMPUTE(0);
    __syncthreads();
    if (t + 1 < 31) { STAGEA(0, KOF(t + 2)); WRITEB(0); }
    if (t + 1 < 30) LOADB(KOF(t + 3));
    COMPUTE(1);
    __syncthreads();
  }
#undef KOF
#undef LOADB
#undef WRITEB
#undef STAGEA
#undef COMPUTE

  // epilogue: C/D layout col=lane&15 (n), row=quad*4+reg (j).
  // per-thread reduce over j, shfl across quads, then cross-waveM reduce via
  // LDS; ONE plain store per (mb, n) -> no atomics, no pre-zeroed buffer.
  float vout[4];
#pragma unroll
  for (int ni = 0; ni < 4; ni++) {
    float v = 0.0f;
#pragma unroll
    for (int mi = 0; mi < 4; mi++) {
      const int jb = aRow0 + waveM * 64 + mi * 16 + quad * 4;
      union { float4_t v4; float f[4]; } u;
      u.v4 = acc[mi][ni];
#pragma unroll
      for (int r = 0; r < 4; r++)
        v += Wmta[jb + r] * tanh_fast(u.f[r]);
    }
    v += __shfl_xor(v, 16);
    v += __shfl_xor(v, 32);
    vout[ni] = v;
  }
  float* sred = (float*)&lA[0][0];   // safe: loop ended with __syncthreads()
  if (waveM == 0 && quad == 0) {
#pragma unroll
    for (int ni = 0; ni < 4; ni++)
      sred[waveN * 64 + ni * 16 + col] = vout[ni];
  }
  __syncthreads();
  if (waveM == 1 && quad == 0) {
#pragma unroll
    for (int ni = 0; ni < 4; ni++) {
      const int n = bRow0 + waveN * 64 + ni * 16 + col;
      sP[(size_t)mb * N_INST + n] = vout[ni] + sred[waveN * 64 + ni * 16 + col];
    }
  }
}

// ---- fused tail: merge partials -> softmax stats (grid sync) -> pool -> linear.
// 256 blocks x 256 threads; all blocks resident (tiny LDS/VGPR at grid=CU
// count) so the arrive-count + flag spin is deadlock-free. Softmax is
// near-one-hot: cold blocks (all w<1e-12) exit before touching V/W; skipped
// terms contribute < 1.6e-7 total.
__global__ __launch_bounds__(256) void k_tail(const float* __restrict__ sP,
                                              const float* __restrict__ V,
                                              const float* __restrict__ W,
                                              float* __restrict__ pstat,
                                              int* __restrict__ ctl,
                                              float* __restrict__ out) {
  __shared__ float wsm[128];
  __shared__ float smM[4], smP[4];
  __shared__ float gstat[2];
  __shared__ float sredc[4][NCLS];
  __shared__ int isLast, hot;
  const int tid = threadIdx.x, lane = tid & 63, wvi = tid >> 6;
  const int n0 = blockIdx.x * 128;

  if (tid == 0) { isLast = 0; hot = 0; }

  // phase 1: s[n] = sum of 4 mb-partials; block-local online (m,p)
  float m = -3.4e38f, p = 0.0f;
  if (tid < 128) {
    float sv = sP[n0 + tid] + sP[N_INST + n0 + tid] +
               sP[2 * N_INST + n0 + tid] + sP[3 * N_INST + n0 + tid];
    wsm[tid] = sv;            // stash raw s for after the sync
    m = sv; p = 1.0f;
  }
  for (int o = 32; o > 0; o >>= 1) {
    float om = __shfl_xor(m, o), op = __shfl_xor(p, o);
    float nm = fmaxf(m, om);
    p = p * __expf(m - nm) + op * __expf(om - nm);
    m = nm;
  }
  if (lane == 0) { smM[wvi] = m; smP[wvi] = p; }
  __syncthreads();
  if (tid == 0) {
    float bm = smM[0], bp = smP[0];
    for (int w2 = 1; w2 < 4; ++w2) {
      float nm = fmaxf(bm, smM[w2]);
      bp = bp * __expf(bm - nm) + smP[w2] * __expf(smM[w2] - nm);
      bm = nm;
    }
    pstat[blockIdx.x * 2]     = bm;
    pstat[blockIdx.x * 2 + 1] = bp;
    __threadfence();
    if (atomicAdd(&ctl[0], 1) == 255) isLast = 1;
  }
  __syncthreads();

  // phase 2: last-arriving block merges all 256 partials, publishes stats
  if (isLast) {
    __threadfence();
    float m2 = pstat[2 * tid], p2 = pstat[2 * tid + 1];
    for (int o = 32; o > 0; o >>= 1) {
      float om = __shfl_xor(m2, o), op = __shfl_xor(p2, o);
      float nm = fmaxf(m2, om);
      p2 = p2 * __expf(m2 - nm) + op * __expf(om - nm);
      m2 = nm;
    }
    if (lane == 0) { smM[wvi] = m2; smP[wvi] = p2; }
    __syncthreads();
    if (tid == 0) {
      float gm = smM[0], gp = smP[0];
      for (int w2 = 1; w2 < 4; ++w2) {
        float nm = fmaxf(gm, smM[w2]);
        gp = gp * __expf(gm - nm) + smP[w2] * __expf(smM[w2] - nm);
        gm = nm;
      }
      pstat[512] = gm;
      pstat[513] = 1.0f / gp;
      __threadfence();
      atomicExch(&ctl[1], 1);
    }
  }

  // phase 3: all blocks wait for the flag, then pool + project
  if (tid == 0) {
    while (atomicAdd(&ctl[1], 0) == 0) __builtin_amdgcn_s_sleep(8);
    __threadfence();
    gstat[0] = pstat[512]; gstat[1] = pstat[513];
  }
  __syncthreads();
  const float mx = gstat[0], inv = gstat[1];
  if (tid < 128) {
    const float w = __expf(wsm[tid] - mx) * inv;
    wsm[tid] = w;
    if (w > 1e-12f) atomicOr(&hot, 1);
  }
  __syncthreads();
  if (hot == 0) return;

  float acc[8] = {0.f, 0.f, 0.f, 0.f, 0.f, 0.f, 0.f, 0.f};
  for (int r = 0; r < 128; ++r) {
    const float w = wsm[r];     // block-uniform branch
    if (w > 1e-12f) {
      const float4* vp = (const float4*)&V[(size_t)(n0 + r) * DIM + tid * 8];
      float4 va = vp[0], vb = vp[1];
      acc[0] += w * va.x; acc[1] += w * va.y; acc[2] += w * va.z; acc[3] += w * va.w;
      acc[4] += w * vb.x; acc[5] += w * vb.y; acc[6] += w * vb.z; acc[7] += w * vb.w;
    }
  }
  // project onto W rows (final linear), block-reduce, one atomicAdd per class
  float pc[NCLS];
#pragma unroll
  for (int c = 0; c < NCLS; ++c) {
    const float4* w4 = (const float4*)&W[(size_t)c * DIM + tid * 8];
    const float4 wa = w4[0], wb = w4[1];
    pc[c] = wa.x * acc[0] + wa.y * acc[1] + wa.z * acc[2] + wa.w * acc[3] +
            wb.x * acc[4] + wb.y * acc[5] + wb.z * acc[6] + wb.w * acc[7];
  }
#pragma unroll
  for (int c = 0; c < NCLS; ++c)
    for (int o = 32; o > 0; o >>= 1) pc[c] += __shfl_xor(pc[c], o);
  if (lane == 0)
#pragma unroll
    for (int c = 0; c < NCLS; ++c) sredc[wvi][c] = pc[c];
  __syncthreads();
  if (tid < NCLS)
    atomicAdd(&out[tid], sredc[0][tid] + sredc[1][tid] +
                         sredc[2][tid] + sredc[3][tid]);
}

extern "C" void kernel_launch(void* const* d_in, const int* in_sizes, int n_in,
                              void* d_out, int out_size, void* d_ws, size_t ws_size,
                              hipStream_t stream) {
  const float* Vp   = (const float*)d_in[0];  // [N, 2048]
  const float* Ut   = (const float*)d_in[1];  // [512, 2048]
  const float* Wmta = (const float*)d_in[2];  // [1, 512]
  const float* W    = (const float*)d_in[3];  // [4, 2048]
  float* out = (float*)d_out;

  char* ws = (char*)d_ws;
  _Float16* Uhi  = (_Float16*)(ws + OFF_UHI);
  float*    sP   = (float*)(ws + OFF_SP);
  float*    pstat= (float*)(ws + OFF_PSTAT);
  int*      ctl  = (int*)(ws + OFF_CTL);

  // 3 dispatches total
  k_cvt<<<(DP * DIM / 8) / 256, 256, 0, stream>>>((const float4*)Ut,
                                                  (half8_t*)Uhi, ctl, out);
  k_score_gemm<<<(DP / 128) * (N_INST / 128), 256, 0, stream>>>(Uhi, Vp, Wmta, sP);
  k_tail<<<N_INST / 128, 256, 0, stream>>>(sP, Vp, W, pstat, ctl, out);
}